// Round 10
// baseline (2753.075 us; speedup 1.0000x reference)
//
#include <hip/hip_runtime.h>
#include <hip/hip_bf16.h>
#include <cstdint>
#include <cstddef>

#define B_    8
#define S_    2048
#define D_    1024
#define DFF_  4096
#define E1_   8
#define E2_   16
#define T_    (B_*S_)
#define CAP1_ 2560
#define CAP2_ 1280
#define EC_   20480   // E1_*CAP1_ == E2_*CAP2_ == padded expert-buffer rows

typedef __bf16 bf16x8 __attribute__((ext_vector_type(8)));
typedef float  f32x4  __attribute__((ext_vector_type(4)));

__device__ __forceinline__ unsigned short f2bf(float x) {
  return __builtin_bit_cast(unsigned short, (__bf16)x);
}

// ---------------- gating: logits = X @ WG, softmax-max + argmax ----------------
template<int E>
__global__ __launch_bounds__(256)
void gate_kernel(const float* __restrict__ X, const float* __restrict__ WG,
                 int* __restrict__ idxO, float* __restrict__ gateO) {
  const int lane = threadIdx.x & 63;
  const int wv   = threadIdx.x >> 6;
  const int t    = blockIdx.x * 4 + wv;
  const float* xr = X + (size_t)t * D_;
  float acc[E];
#pragma unroll
  for (int e = 0; e < E; ++e) acc[e] = 0.f;
#pragma unroll
  for (int i = 0; i < 4; ++i) {
    float4 xv = *(const float4*)(xr + i * 256 + lane * 4);
    int kb = i * 256 + lane * 4;
#pragma unroll
    for (int j = 0; j < 4; ++j) {
      float xs = (&xv.x)[j];
      const float* wr = WG + (size_t)(kb + j) * E;
#pragma unroll
      for (int e = 0; e < E; ++e) acc[e] += xs * wr[e];
    }
  }
#pragma unroll
  for (int e = 0; e < E; ++e) {
    float v = acc[e];
#pragma unroll
    for (int s = 32; s >= 1; s >>= 1) v += __shfl_xor(v, s, 64);
    acc[e] = v;
  }
  if (lane == 0) {
    float mx = acc[0]; int mi = 0;
#pragma unroll
    for (int e = 1; e < E; ++e) if (acc[e] > mx) { mx = acc[e]; mi = e; }
    float s = 0.f;
#pragma unroll
    for (int e = 0; e < E; ++e) s += expf(acc[e] - mx);
    idxO[t]  = mi;
    gateO[t] = 1.0f / s;   // max softmax prob
  }
}

// ---------------- order-preserving per-expert position scan ----------------
__global__ __launch_bounds__(1024)
void scan_kernel(const int* __restrict__ idx, int E, int cap,
                 int* __restrict__ pos, int* __restrict__ kept) {
  __shared__ int cnt[16][17];
  __shared__ int gbase[16];
  const int tid = threadIdx.x;
  const int w = tid >> 6, lane = tid & 63;
  if (tid < E) gbase[tid] = 0;
  __syncthreads();
  const unsigned long long lt = (lane == 63) ? 0xFFFFFFFFFFFFFFFFull >> 1
                                             : ((1ull << lane) - 1ull);
  for (int it = 0; it < T_ / 1024; ++it) {
    int t = it * 1024 + tid;
    int mi = idx[t];
    int rank = 0;
    for (int e = 0; e < E; ++e) {
      unsigned long long m = __ballot(mi == e);
      if (lane == 0) cnt[w][e] = __popcll(m);
      if (mi == e) rank = __popcll(m & lt);
    }
    __syncthreads();
    int off = 0;
    for (int w2 = 0; w2 < w; ++w2) off += cnt[w2][mi];
    pos[t] = gbase[mi] + off + rank;
    __syncthreads();
    if (tid < E) {
      int tot = 0;
      for (int w2 = 0; w2 < 16; ++w2) tot += cnt[w2][tid];
      gbase[tid] += tot;
    }
    __syncthreads();
  }
  if (tid < E) kept[tid] = min(gbase[tid], cap);
}

// ---------------- scatter tokens to expert buffers (f32 -> bf16) ----------------
__global__ __launch_bounds__(64)
void scatter_kernel(const float* __restrict__ X, const int* __restrict__ idx,
                    const int* __restrict__ pos, int cap,
                    unsigned short* __restrict__ xbuf, int* __restrict__ tokmap,
                    float* __restrict__ mzero) {
  const int t = blockIdx.x;
  const int lane = threadIdx.x;
  const int p = pos[t];
  if (p < cap) {
    const size_t dst = ((size_t)idx[t] * cap + p) * D_;
    const float* xr = X + (size_t)t * D_;
#pragma unroll
    for (int i = 0; i < 4; ++i) {
      float4 v = *(const float4*)(xr + i * 256 + lane * 4);
      ushort4 o;
      o.x = f2bf(v.x); o.y = f2bf(v.y); o.z = f2bf(v.z); o.w = f2bf(v.w);
      *(ushort4*)(xbuf + dst + i * 256 + lane * 4) = o;
    }
    if (lane == 0) tokmap[(size_t)idx[t] * cap + p] = t;
  } else {
    float4 z = {0.f, 0.f, 0.f, 0.f};
    float* mr = mzero + (size_t)t * D_;
#pragma unroll
    for (int i = 0; i < 4; ++i) *(float4*)(mr + i * 256 + lane * 4) = z;
  }
}

// ---------------- weight transpose+convert: [K][N] f32 -> [N][K] bf16 ----------------
__global__ __launch_bounds__(256)
void wtrans_kernel(const float* __restrict__ src, unsigned short* __restrict__ dst,
                   int K, int N) {
  __shared__ float t[64][65];
  const int tid = threadIdx.x;
  const size_t eo = (size_t)blockIdx.z * K * N;
  const int k0 = blockIdx.y * 64, n0 = blockIdx.x * 64;
  const float* s = src + eo + (size_t)k0 * N + n0;
  unsigned short* d = dst + eo + (size_t)n0 * K + k0;
#pragma unroll
  for (int i = 0; i < 4; ++i) {
    int k = i * 16 + (tid >> 4);
    int n4 = (tid & 15) * 4;
    float4 v = *(const float4*)(s + (size_t)k * N + n4);
    t[k][n4] = v.x; t[k][n4 + 1] = v.y; t[k][n4 + 2] = v.z; t[k][n4 + 3] = v.w;
  }
  __syncthreads();
#pragma unroll
  for (int i = 0; i < 4; ++i) {
    int n = i * 16 + (tid >> 4);
    int k4 = (tid & 15) * 4;
    ushort4 o;
    o.x = f2bf(t[k4][n]);     o.y = f2bf(t[k4 + 1][n]);
    o.z = f2bf(t[k4 + 2][n]); o.w = f2bf(t[k4 + 3][n]);
    *(ushort4*)(d + (size_t)n * K + k4) = o;
  }
}

// ---------------- expert GEMM (128x128, BK=64, SINGLE buffer, 4 blocks/CU) -----
// Cross-block wave overlap (m114/m97 mechanism) hides the stage/barrier stall.
// First ntb blocks (if tsrc) are dedicated transpose workers for the NEXT weight
// (f32 [tE][tK][tN] -> bf16 [tE][tN][tK]); they co-run with GEMM blocks.
// MODE 0: Hout = relu(C) bf16.  MODE 1: Mout[tok] = C * gate[tok] (gather).
template<int MODE>
__global__ __launch_bounds__(256, 4)
void moe_gemm(const unsigned short* __restrict__ A,
              const unsigned short* __restrict__ BT,
              const float* __restrict__ bias, int K, int N, int cap, int nbcnt,
              const int* __restrict__ kept,
              unsigned short* __restrict__ Hout, float* __restrict__ Mout,
              const int* __restrict__ tokmap, const float* __restrict__ gate,
              const float* __restrict__ tsrc, unsigned short* __restrict__ tdst,
              int tK, int tN, int tE, int ntb) {
  __shared__ char smem[32768];   // GEMM: A 16KB | B 16KB.  Transpose: 64x65 f32.
  const int tid = threadIdx.x;

  // ---- dedicated transpose-worker blocks ----
  if (tsrc != nullptr && (int)blockIdx.x < ntb) {
    float (*tt)[65] = (float(*)[65])smem;
    const int ntn = tN >> 6, ntk = tK >> 6;
    const int tiles = tE * ntk * ntn;
    for (int t = blockIdx.x; t < tiles; t += ntb) {
      const int e2 = t / (ntk * ntn), rem = t - e2 * (ntk * ntn);
      const int k0 = (rem / ntn) << 6, n0 = (rem - (rem / ntn) * ntn) << 6;
      const float* s = tsrc + (size_t)e2 * tK * tN + (size_t)k0 * tN + n0;
      unsigned short* d2 = tdst + (size_t)e2 * tK * tN + (size_t)n0 * tK + k0;
#pragma unroll
      for (int i = 0; i < 4; ++i) {
        int k = i * 16 + (tid >> 4);
        int n4 = (tid & 15) * 4;
        float4 v = *(const float4*)(s + (size_t)k * tN + n4);
        tt[k][n4] = v.x; tt[k][n4 + 1] = v.y; tt[k][n4 + 2] = v.z; tt[k][n4 + 3] = v.w;
      }
      __syncthreads();
#pragma unroll
      for (int i = 0; i < 4; ++i) {
        int n = i * 16 + (tid >> 4);
        int k4 = (tid & 15) * 4;
        ushort4 o;
        o.x = f2bf(tt[k4][n]);     o.y = f2bf(tt[k4 + 1][n]);
        o.z = f2bf(tt[k4 + 2][n]); o.w = f2bf(tt[k4 + 3][n]);
        *(ushort4*)(d2 + (size_t)n * tK + k4) = o;
      }
      __syncthreads();
    }
    return;
  }

  const int gbid = tsrc ? ((int)blockIdx.x - ntb) : (int)blockIdx.x;
  const int ngb  = tsrc ? ((int)gridDim.x - ntb) : (int)gridDim.x;
  const int lane = tid & 63;
  const int wv   = tid >> 6;
  const int wr   = wv >> 1, wc = wv & 1;

  // XCD-chunk swizzle + group-of-8-mb for L2 locality
  const int wg  = (gbid & 7) * (ngb >> 3) + (gbid >> 3);
  const int per_grp = nbcnt * 8;
  const int grp = wg / per_grp;
  const int rem = wg - grp * per_grp;
  const int mb  = grp * 8 + (rem & 7);
  const int nb  = rem >> 3;

  const int e  = (mb * 128) / cap;
  const int r0 = mb * 128 - e * cap;
  const int kept_e = kept[e];
  if (r0 >= kept_e) return;
  const unsigned short* Ab = A + (size_t)(mb * 128) * K;
  const unsigned short* Bb = BT + ((size_t)e * N + (size_t)nb * 128) * K;

  f32x4 acc[4][4];
#pragma unroll
  for (int m = 0; m < 4; ++m)
#pragma unroll
    for (int n = 0; n < 4; ++n) acc[m][n] = (f32x4){0.f, 0.f, 0.f, 0.f};

  // stage one K-tile (128 rows x 64 k, A and B); source pre-swizzled
  auto stage = [&](int k0) {
#pragma unroll
    for (int j = 0; j < 4; ++j) {
      const int c   = j * 256 + tid;       // chunk id 0..1023
      const int row = c >> 3;              // 8 x 16B chunks per 128B row
      const int cc  = c & 7;
      const int scol = (cc ^ (row & 7)) << 3;   // source col in elements
      const unsigned short* ga = Ab + (size_t)row * K + k0 + scol;
      const unsigned short* gb = Bb + (size_t)row * K + k0 + scol;
      char* la = smem + (j * 256 + (tid & ~63)) * 16;
      char* lb = la + 16384;
      __builtin_amdgcn_global_load_lds((const __attribute__((address_space(1))) void*)ga,
                                       (__attribute__((address_space(3))) void*)la,
                                       16, 0, 0);
      __builtin_amdgcn_global_load_lds((const __attribute__((address_space(1))) void*)gb,
                                       (__attribute__((address_space(3))) void*)lb,
                                       16, 0, 0);
    }
  };

  const int NT = K >> 6;
  const int g16 = (lane >> 4) * 16;
  const int r16 = lane & 15;

  for (int t = 0; t < NT; ++t) {
    stage(t << 6);
    __syncthreads();           // staging complete (compiler drains vmcnt)

    const char* As = smem;
    const char* Bs = smem + 16384;
    bf16x8 af[4][2], bfr[4][2];
#pragma unroll
    for (int m = 0; m < 4; ++m) {
      const int row = wr * 64 + m * 16 + r16;
      const int sw  = (row & 7) << 4;
#pragma unroll
      for (int ks = 0; ks < 2; ++ks)
        af[m][ks] = *(const bf16x8*)(As + row * 128 + ((ks * 64 + g16) ^ sw));
    }
#pragma unroll
    for (int n = 0; n < 4; ++n) {
      const int row = wc * 64 + n * 16 + r16;
      const int sw  = (row & 7) << 4;
#pragma unroll
      for (int ks = 0; ks < 2; ++ks)
        bfr[n][ks] = *(const bf16x8*)(Bs + row * 128 + ((ks * 64 + g16) ^ sw));
    }
    __builtin_amdgcn_s_setprio(1);
#pragma unroll
    for (int ks = 0; ks < 2; ++ks)
#pragma unroll
      for (int m = 0; m < 4; ++m)
#pragma unroll
        for (int n = 0; n < 4; ++n)
          acc[m][n] = __builtin_amdgcn_mfma_f32_16x16x32_bf16(af[m][ks], bfr[n][ks], acc[m][n], 0, 0, 0);
    __builtin_amdgcn_s_setprio(0);
    __syncthreads();           // all reads done before next stage overwrites
  }

  // epilogue
  const int rg = lane >> 4;
  float bv[4];
#pragma unroll
  for (int n = 0; n < 4; ++n)
    bv[n] = bias[(size_t)e * N + nb * 128 + wc * 64 + n * 16 + r16];

#pragma unroll
  for (int m = 0; m < 4; ++m) {
#pragma unroll
    for (int r = 0; r < 4; ++r) {
      const int lrow = wr * 64 + m * 16 + rg * 4 + r;
      if (MODE == 0) {
        unsigned short* orow = Hout + (size_t)(mb * 128 + lrow) * N + nb * 128;
#pragma unroll
        for (int n = 0; n < 4; ++n) {
          float v = acc[m][n][r] + bv[n];
          orow[wc * 64 + n * 16 + r16] = f2bf(fmaxf(v, 0.f));
        }
      } else {
        const int lr = r0 + lrow;
        if (lr < kept_e) {
          const int tok = tokmap[mb * 128 + lrow];
          const float gsc = gate[tok];
          float* orow = Mout + (size_t)tok * N + nb * 128;
#pragma unroll
          for (int n = 0; n < 4; ++n)
            orow[wc * 64 + n * 16 + r16] = (acc[m][n][r] + bv[n]) * gsc;
        }
      }
    }
  }
}

// ---------------- residual + mean over S ----------------
__global__ __launch_bounds__(256)
void reduce_kernel(const float* __restrict__ X, const float* __restrict__ M2,
                   float* __restrict__ sent) {
  const int c = blockIdx.x * 256 + threadIdx.x;   // 0..1023
  const int b = blockIdx.z;
  const int s0 = blockIdx.y * 128;
  float a = 0.f;
  size_t base = ((size_t)b * S_ + s0) * D_ + c;
  for (int s = 0; s < 128; ++s) a += X[base + (size_t)s * D_] + M2[base + (size_t)s * D_];
  atomicAdd(&sent[b * D_ + c], a * (1.0f / (float)S_));
}

// ---------------- logsumexp NLL loss ----------------
__global__ __launch_bounds__(64)
void loss_kernel(const float* __restrict__ sent, const int* __restrict__ y,
                 float* __restrict__ out) {
  const int lane = threadIdx.x;
  float total = 0.f;
  for (int b = 0; b < B_; ++b) {
    const float* s = sent + b * D_;
    float v[16];
    float mx = -1e30f;
#pragma unroll
    for (int i = 0; i < 16; ++i) { v[i] = s[lane + i * 64]; mx = fmaxf(mx, v[i]); }
#pragma unroll
    for (int sh = 32; sh >= 1; sh >>= 1) mx = fmaxf(mx, __shfl_xor(mx, sh, 64));
    float sm = 0.f;
#pragma unroll
    for (int i = 0; i < 16; ++i) sm += expf(v[i] - mx);
#pragma unroll
    for (int sh = 32; sh >= 1; sh >>= 1) sm += __shfl_xor(sm, sh, 64);
    total += logf(sm) + mx - s[y[b]];
  }
  if (lane == 0) out[0] = total * (1.0f / (float)B_);
}

extern "C" void kernel_launch(void* const* d_in, const int* in_sizes, int n_in,
                              void* d_out, int out_size, void* d_ws, size_t ws_size,
                              hipStream_t stream) {
  const float* x   = (const float*)d_in[0];
  const int*   y   = (const int*)d_in[1];
  const float* wg1 = (const float*)d_in[2];
  const float* w1a = (const float*)d_in[3];
  const float* b1a = (const float*)d_in[4];
  const float* w2a = (const float*)d_in[5];
  const float* b2a = (const float*)d_in[6];
  const float* wg2 = (const float*)d_in[7];
  const float* w1b = (const float*)d_in[8];
  const float* b1b = (const float*)d_in[9];
  const float* w2b = (const float*)d_in[10];
  const float* b2b = (const float*)d_in[11];
  float* out = (float*)d_out;
  (void)in_sizes; (void)n_in; (void)out_size;

  char* base = (char*)d_ws;
  size_t o = 0;
  auto alloc = [&](size_t bytes) { size_t r = o; o = (o + bytes + 255) & ~(size_t)255; return r; };
  int*   idx1    = (int*)  (base + alloc((size_t)T_ * 4));
  int*   pos1    = (int*)  (base + alloc((size_t)T_ * 4));
  float* gate1   = (float*)(base + alloc((size_t)T_ * 4));
  int*   idx2    = (int*)  (base + alloc((size_t)T_ * 4));
  int*   pos2    = (int*)  (base + alloc((size_t)T_ * 4));
  float* gate2   = (float*)(base + alloc((size_t)T_ * 4));
  int*   kept1   = (int*)  (base + alloc(64 * 4));
  int*   kept2   = (int*)  (base + alloc(64 * 4));
  int*   tokmap1 = (int*)  (base + alloc((size_t)EC_ * 4));
  int*   tokmap2 = (int*)  (base + alloc((size_t)EC_ * 4));
  float* sent    = (float*)(base + alloc((size_t)B_ * D_ * 4));
  float* m1      = (float*)(base + alloc((size_t)T_ * D_ * 4));   // layer-1 out, reused as layer-2 out
  unsigned short* xbuf = (unsigned short*)(base + alloc((size_t)EC_ * D_ * 2));    // 40 MB
  unsigned short* h    = (unsigned short*)(base + alloc((size_t)EC_ * DFF_ * 2));  // 160 MB
  unsigned short* P1   = (unsigned short*)(base + alloc((size_t)E2_ * D_ * DFF_ * 2)); // 128 MB: W1^T chain
  size_t need_with_P2 = o + (size_t)E2_ * D_ * DFF_ * 2 + 256;
  const bool fold = (ws_size >= need_with_P2);
  unsigned short* P2 = fold ? (unsigned short*)(base + alloc((size_t)E2_ * D_ * DFF_ * 2))
                            : P1;   // fallback: single buffer, serial wtrans chain

  hipMemsetAsync(sent, 0, (size_t)B_ * D_ * 4, stream);

  const int G0  = (DFF_ / 128) * (EC_ / 128);   // 5120 GEMM blocks
  const int G1  = (D_  / 128) * (EC_ / 128);    // 1280 GEMM blocks
  const int NTB = 256;                          // transpose-worker blocks

  // ----- layer 1 (E=8, cap=2560) -----
  gate_kernel<E1_><<<T_ / 4, 256, 0, stream>>>(x, wg1, idx1, gate1);
  scan_kernel<<<1, 1024, 0, stream>>>(idx1, E1_, CAP1_, pos1, kept1);
  scatter_kernel<<<T_, 64, 0, stream>>>(x, idx1, pos1, CAP1_, xbuf, tokmap1, m1);
  wtrans_kernel<<<dim3(DFF_ / 64, D_ / 64, E1_), 256, 0, stream>>>(w1a, P1, D_, DFF_);
  if (fold) {
    moe_gemm<0><<<G0 + NTB, 256, 0, stream>>>(xbuf, P1, b1a, D_, DFF_, CAP1_, DFF_ / 128,
        kept1, h, nullptr, nullptr, nullptr, w2a, P2, DFF_, D_, E1_, NTB);
    moe_gemm<1><<<G1 + NTB, 256, 0, stream>>>(h, P2, b2a, DFF_, D_, CAP1_, D_ / 128,
        kept1, nullptr, m1, tokmap1, gate1, w1b, P1, D_, DFF_, E2_, NTB);
  } else {
    moe_gemm<0><<<G0, 256, 0, stream>>>(xbuf, P1, b1a, D_, DFF_, CAP1_, DFF_ / 128,
        kept1, h, nullptr, nullptr, nullptr, nullptr, nullptr, 0, 0, 0, 0);
    wtrans_kernel<<<dim3(D_ / 64, DFF_ / 64, E1_), 256, 0, stream>>>(w2a, P2, DFF_, D_);
    moe_gemm<1><<<G1, 256, 0, stream>>>(h, P2, b2a, DFF_, D_, CAP1_, D_ / 128,
        kept1, nullptr, m1, tokmap1, gate1, nullptr, nullptr, 0, 0, 0, 0);
    wtrans_kernel<<<dim3(DFF_ / 64, D_ / 64, E2_), 256, 0, stream>>>(w1b, P1, D_, DFF_);
  }

  // ----- layer 2 (E=16, cap=1280) -----
  gate_kernel<E2_><<<T_ / 4, 256, 0, stream>>>(m1, wg2, idx2, gate2);
  scan_kernel<<<1, 1024, 0, stream>>>(idx2, E2_, CAP2_, pos2, kept2);
  scatter_kernel<<<T_, 64, 0, stream>>>(m1, idx2, pos2, CAP2_, xbuf, tokmap2, m1);
  if (fold) {
    moe_gemm<0><<<G0 + NTB, 256, 0, stream>>>(xbuf, P1, b1b, D_, DFF_, CAP2_, DFF_ / 128,
        kept2, h, nullptr, nullptr, nullptr, w2b, P2, DFF_, D_, E2_, NTB);
    moe_gemm<1><<<G1, 256, 0, stream>>>(h, P2, b2b, DFF_, D_, CAP2_, D_ / 128,
        kept2, nullptr, m1, tokmap2, gate2, nullptr, nullptr, 0, 0, 0, 0);
  } else {
    moe_gemm<0><<<G0, 256, 0, stream>>>(xbuf, P1, b1b, D_, DFF_, CAP2_, DFF_ / 128,
        kept2, h, nullptr, nullptr, nullptr, nullptr, nullptr, 0, 0, 0, 0);
    wtrans_kernel<<<dim3(D_ / 64, DFF_ / 64, E2_), 256, 0, stream>>>(w2b, P2, DFF_, D_);
    moe_gemm<1><<<G1, 256, 0, stream>>>(h, P2, b2b, DFF_, D_, CAP2_, D_ / 128,
        kept2, nullptr, m1, tokmap2, gate2, nullptr, nullptr, 0, 0, 0, 0);
  }

  // ----- residual + mean + loss -----
  reduce_kernel<<<dim3(D_ / 256, S_ / 128, B_), 256, 0, stream>>>(x, m1, sent);
  loss_kernel<<<1, 64, 0, stream>>>(sent, y, out);
}

// Round 11
// 1536.453 us; speedup vs baseline: 1.7918x; 1.7918x over previous
//
#include <hip/hip_runtime.h>
#include <hip/hip_bf16.h>
#include <cstdint>
#include <cstddef>

#define B_    8
#define S_    2048
#define D_    1024
#define DFF_  4096
#define E1_   8
#define E2_   16
#define T_    (B_*S_)
#define CAP1_ 2560
#define CAP2_ 1280
#define EC_   20480   // E1_*CAP1_ == E2_*CAP2_ == padded expert-buffer rows

typedef __bf16 bf16x8 __attribute__((ext_vector_type(8)));
typedef float  f32x4  __attribute__((ext_vector_type(4)));

__device__ __forceinline__ unsigned short f2bf(float x) {
  return __builtin_bit_cast(unsigned short, (__bf16)x);
}

// ---------------- gating: logits = X @ WG, softmax-max + argmax ----------------
template<int E>
__global__ __launch_bounds__(256)
void gate_kernel(const float* __restrict__ X, const float* __restrict__ WG,
                 int* __restrict__ idxO, float* __restrict__ gateO) {
  const int lane = threadIdx.x & 63;
  const int wv   = threadIdx.x >> 6;
  const int t    = blockIdx.x * 4 + wv;
  const float* xr = X + (size_t)t * D_;
  float acc[E];
#pragma unroll
  for (int e = 0; e < E; ++e) acc[e] = 0.f;
#pragma unroll
  for (int i = 0; i < 4; ++i) {
    float4 xv = *(const float4*)(xr + i * 256 + lane * 4);
    int kb = i * 256 + lane * 4;
#pragma unroll
    for (int j = 0; j < 4; ++j) {
      float xs = (&xv.x)[j];
      const float* wr = WG + (size_t)(kb + j) * E;
#pragma unroll
      for (int e = 0; e < E; ++e) acc[e] += xs * wr[e];
    }
  }
#pragma unroll
  for (int e = 0; e < E; ++e) {
    float v = acc[e];
#pragma unroll
    for (int s = 32; s >= 1; s >>= 1) v += __shfl_xor(v, s, 64);
    acc[e] = v;
  }
  if (lane == 0) {
    float mx = acc[0]; int mi = 0;
#pragma unroll
    for (int e = 1; e < E; ++e) if (acc[e] > mx) { mx = acc[e]; mi = e; }
    float s = 0.f;
#pragma unroll
    for (int e = 0; e < E; ++e) s += expf(acc[e] - mx);
    idxO[t]  = mi;
    gateO[t] = 1.0f / s;   // max softmax prob
  }
}

// ---------------- order-preserving per-expert position scan ----------------
__global__ __launch_bounds__(1024)
void scan_kernel(const int* __restrict__ idx, int E, int cap,
                 int* __restrict__ pos, int* __restrict__ kept) {
  __shared__ int cnt[16][17];
  __shared__ int gbase[16];
  const int tid = threadIdx.x;
  const int w = tid >> 6, lane = tid & 63;
  if (tid < E) gbase[tid] = 0;
  __syncthreads();
  const unsigned long long lt = (lane == 63) ? 0xFFFFFFFFFFFFFFFFull >> 1
                                             : ((1ull << lane) - 1ull);
  for (int it = 0; it < T_ / 1024; ++it) {
    int t = it * 1024 + tid;
    int mi = idx[t];
    int rank = 0;
    for (int e = 0; e < E; ++e) {
      unsigned long long m = __ballot(mi == e);
      if (lane == 0) cnt[w][e] = __popcll(m);
      if (mi == e) rank = __popcll(m & lt);
    }
    __syncthreads();
    int off = 0;
    for (int w2 = 0; w2 < w; ++w2) off += cnt[w2][mi];
    pos[t] = gbase[mi] + off + rank;
    __syncthreads();
    if (tid < E) {
      int tot = 0;
      for (int w2 = 0; w2 < 16; ++w2) tot += cnt[w2][tid];
      gbase[tid] += tot;
    }
    __syncthreads();
  }
  if (tid < E) kept[tid] = min(gbase[tid], cap);
}

// ---------------- scatter tokens to expert buffers (f32 -> bf16) ----------------
__global__ __launch_bounds__(64)
void scatter_kernel(const float* __restrict__ X, const int* __restrict__ idx,
                    const int* __restrict__ pos, int cap,
                    unsigned short* __restrict__ xbuf, int* __restrict__ tokmap,
                    float* __restrict__ mzero) {
  const int t = blockIdx.x;
  const int lane = threadIdx.x;
  const int p = pos[t];
  if (p < cap) {
    const size_t dst = ((size_t)idx[t] * cap + p) * D_;
    const float* xr = X + (size_t)t * D_;
#pragma unroll
    for (int i = 0; i < 4; ++i) {
      float4 v = *(const float4*)(xr + i * 256 + lane * 4);
      ushort4 o;
      o.x = f2bf(v.x); o.y = f2bf(v.y); o.z = f2bf(v.z); o.w = f2bf(v.w);
      *(ushort4*)(xbuf + dst + i * 256 + lane * 4) = o;
    }
    if (lane == 0) tokmap[(size_t)idx[t] * cap + p] = t;
  } else {
    float4 z = {0.f, 0.f, 0.f, 0.f};
    float* mr = mzero + (size_t)t * D_;
#pragma unroll
    for (int i = 0; i < 4; ++i) *(float4*)(mr + i * 256 + lane * 4) = z;
  }
}

// ---------------- weight transpose+convert: [K][N] f32 -> [N][K] bf16 ----------------
__global__ __launch_bounds__(256)
void wtrans_kernel(const float* __restrict__ src, unsigned short* __restrict__ dst,
                   int K, int N) {
  __shared__ float t[64][65];
  const int tid = threadIdx.x;
  const size_t eo = (size_t)blockIdx.z * K * N;
  const int k0 = blockIdx.y * 64, n0 = blockIdx.x * 64;
  const float* s = src + eo + (size_t)k0 * N + n0;
  unsigned short* d = dst + eo + (size_t)n0 * K + k0;
#pragma unroll
  for (int i = 0; i < 4; ++i) {
    int k = i * 16 + (tid >> 4);
    int n4 = (tid & 15) * 4;
    float4 v = *(const float4*)(s + (size_t)k * N + n4);
    t[k][n4] = v.x; t[k][n4 + 1] = v.y; t[k][n4 + 2] = v.z; t[k][n4 + 3] = v.w;
  }
  __syncthreads();
#pragma unroll
  for (int i = 0; i < 4; ++i) {
    int n = i * 16 + (tid >> 4);
    int k4 = (tid & 15) * 4;
    ushort4 o;
    o.x = f2bf(t[k4][n]);     o.y = f2bf(t[k4 + 1][n]);
    o.z = f2bf(t[k4 + 2][n]); o.w = f2bf(t[k4 + 3][n]);
    *(ushort4*)(d + (size_t)n * K + k4) = o;
  }
}

// -------- expert GEMM: PERSISTENT 256x256 / BK=64 / 8-phase counted-vmcnt ------
// Grid = 256 blocks; block walks tiles {bid, bid+G, ...} (inactive skipped).
// Ring stays hot across tile boundaries: boundary iteration stages next tile's
// first 2 K-tiles into the same slots; epilogue C-write overlaps those loads.
#define STG(BASEPTR, H, KT, SLOT) do {                                          \
    const unsigned short* _s = (BASEPTR) + (size_t)((H) * 128) * K + (KT) + st_off; \
    __builtin_amdgcn_global_load_lds((const __attribute__((address_space(1))) void*)_s, \
        (__attribute__((address_space(3))) void*)(smem + (SLOT) + dst0), 16, 0, 0);   \
    __builtin_amdgcn_global_load_lds((const __attribute__((address_space(1))) void*)(_s + (size_t)64 * K), \
        (__attribute__((address_space(3))) void*)(smem + (SLOT) + 8192 + dst0), 16, 0, 0); \
  } while (0)

#define RDA(BUF, MH) do { _Pragma("unroll")                                     \
    for (int m_ = 0; m_ < 4; ++m_) {                                            \
      const char* _p = smem + (BUF) * 65536 + aslot + ((MH) * 4 + m_) * 2048;   \
      af[m_][0] = *(const bf16x8*)(_p + va);                                    \
      af[m_][1] = *(const bf16x8*)(_p + (va ^ 64)); } } while (0)

#define RDB(BUF, NH) do { _Pragma("unroll")                                     \
    for (int j_ = 0; j_ < 2; ++j_) {                                            \
      const char* _p = smem + (BUF) * 65536 + bslot + ((NH) * 2 + j_) * 2048;   \
      bf[(NH) * 2 + j_][0] = *(const bf16x8*)(_p + vb);                         \
      bf[(NH) * 2 + j_][1] = *(const bf16x8*)(_p + (vb ^ 64)); } } while (0)

#define QUAD(MH, NH) do {                                                       \
    __builtin_amdgcn_s_setprio(1);                                              \
    _Pragma("unroll") for (int m_ = 0; m_ < 4; ++m_)                            \
    _Pragma("unroll") for (int j_ = 0; j_ < 2; ++j_)                            \
    _Pragma("unroll") for (int k_ = 0; k_ < 2; ++k_)                            \
      acc[(MH) * 4 + m_][(NH) * 2 + j_] = __builtin_amdgcn_mfma_f32_16x16x32_bf16( \
          af[m_][k_], bf[(NH) * 2 + j_][k_], acc[(MH) * 4 + m_][(NH) * 2 + j_], 0, 0, 0); \
    __builtin_amdgcn_s_setprio(0);                                              \
  } while (0)

#define SB0   __builtin_amdgcn_sched_barrier(0)
#define BAR   __builtin_amdgcn_s_barrier()
#define VM6   do { asm volatile("s_waitcnt vmcnt(6)" ::: "memory"); SB0; } while (0)
#define VM8   do { asm volatile("s_waitcnt vmcnt(8)" ::: "memory"); SB0; } while (0)
#define VM0   do { asm volatile("s_waitcnt vmcnt(0)" ::: "memory"); SB0; } while (0)

template<int MODE>
__global__ __launch_bounds__(512, 2)
void moe_gemm(const unsigned short* __restrict__ A,
              const unsigned short* __restrict__ BT,
              const float* __restrict__ bias, int K, int N, int cap, int nbcnt,
              int ntiles,
              const int* __restrict__ kept,
              unsigned short* __restrict__ Hout, float* __restrict__ Mout,
              const int* __restrict__ tokmap, const float* __restrict__ gate) {
  __shared__ char smem[131072];
  const int tid  = threadIdx.x;
  const int lane = tid & 63;
  const int wv   = tid >> 6;      // 0..7
  const int wr   = wv >> 2;       // 0..1 (M half)
  const int wc   = wv & 3;        // 0..3 (N quarter)
  const int G    = gridDim.x;
  const int per_grp = nbcnt * 4;
  const int chunk   = ntiles >> 3;

  // staging addressing: chunk row = tid>>3 (0..63), cc = tid&7; src pre-swizzled
  const int scol   = ((tid & 7) ^ ((tid >> 3) & 7)) * 8;
  const size_t st_off = (size_t)(tid >> 3) * K + scol;
  const int dst0   = tid * 16;

  // fragment read addressing
  const int r16 = lane & 15;
  const int g16 = (lane >> 4) * 16;
  const int swz = (r16 & 7) * 16;
  const int va  = r16 * 128 + (g16 ^ swz);
  const int vb  = (wc & 1) * 8192 + va;
  const int aslot = wr * 16384;
  const int bslot = 32768 + (wc >> 1) * 16384;
  bf16x8 af[4][2], bf[4][2];

  f32x4 acc[8][4];
#pragma unroll
  for (int m = 0; m < 8; ++m)
#pragma unroll
    for (int n = 0; n < 4; ++n) acc[m][n] = (f32x4){0.f, 0.f, 0.f, 0.f};

  auto tinfo = [&](int t, int& mb, int& nb, int& e, int& r0) {
    const int wgx = (t & 7) * chunk + (t >> 3);
    const int grp = wgx / per_grp;
    const int rem = wgx - grp * per_grp;
    mb = grp * 4 + (rem & 3);
    nb = rem >> 2;
    e  = (mb * 256) / cap;
    r0 = mb * 256 - e * cap;
  };

  // find first active tile
  int tc = blockIdx.x, mbC = 0, nbC = 0, eC = 0, r0C = 0, keptC = 0;
  for (; tc < ntiles; tc += G) {
    tinfo(tc, mbC, nbC, eC, r0C);
    keptC = kept[eC];
    if (r0C < keptC) break;
  }
  if (tc >= ntiles) return;
  const unsigned short* AbC = A + (size_t)(mbC * 256) * K;
  const unsigned short* BbC = BT + ((size_t)eC * N + (size_t)nbC * 256) * K;

  // find next active tile
  int tn = tc + G, mbN = 0, nbN = 0, eN = 0, r0N = 0, keptN = 0;
  for (; tn < ntiles; tn += G) {
    tinfo(tn, mbN, nbN, eN, r0N);
    keptN = kept[eN];
    if (r0N < keptN) break;
  }
  bool hasN = tn < ntiles;
  const unsigned short* AbN = hasN ? A + (size_t)(mbN * 256) * K : AbC;
  const unsigned short* BbN = hasN ? BT + ((size_t)eN * N + (size_t)nbN * 256) * K : BbC;

  // slot offsets: buf0 A0=0 A1=16384 B0=32768 B1=49152 ; buf1 +65536
  // prologue: stage cur tile K-tiles 0 and 64 (all 8 slots)
  STG(AbC, 0, 0, 0);
  STG(BbC, 0, 0, 32768);
  STG(BbC, 1, 0, 49152);
  STG(AbC, 1, 0, 16384);
  STG(AbC, 0, 64, 65536);
  STG(BbC, 0, 64, 98304);
  STG(BbC, 1, 64, 114688);
  STG(AbC, 1, 64, 81920);
  VM8; BAR;

  const int NI = K >> 7;   // 2 K-tiles per iteration
  bool first = true;

  for (;;) {
    for (int i = 0; i < NI; ++i) {
      const int kt1 = (2 * i + 1) << 6;
      const int kt2 = (2 * i + 2) << 6;
      const int kt3 = kt2 + 64;
      const bool bnd = (kt2 >= K);   // true only at i == NI-1

      // ph1: reads buf0 A0,B0 ; stage buf1.A1 <- cur kt1
      RDA(0, 0); RDB(0, 0);
      if (i > 0 || !first) STG(AbC, 1, kt1, 81920);
      BAR; QUAD(0, 0); BAR;
      // ph2: reads buf0.B1 ; stage buf0.A0
      RDB(0, 1);
      if (!bnd) STG(AbC, 0, kt2, 0); else if (hasN) STG(AbN, 0, 0, 0);
      BAR; QUAD(0, 1); BAR;
      // ph3: reads buf0.A1 ; stage buf0.B0
      RDA(0, 1);
      if (!bnd) STG(BbC, 0, kt2, 32768); else if (hasN) STG(BbN, 0, 0, 32768);
      BAR; QUAD(1, 1); BAR;
      // ph4: stage buf0.B1 ; checkpoint
      if (!bnd) STG(BbC, 1, kt2, 49152); else if (hasN) STG(BbN, 1, 0, 49152);
      if (bnd && !hasN) { VM0; } else { VM6; }
      BAR; QUAD(1, 0); BAR;
      // ph5: reads buf1 A0,B0 ; stage buf0.A1
      RDA(1, 0); RDB(1, 0);
      if (!bnd) STG(AbC, 1, kt2, 16384); else if (hasN) STG(AbN, 1, 0, 16384);
      BAR; QUAD(0, 0); BAR;
      // ph6: reads buf1.B1 ; stage buf1.A0
      RDB(1, 1);
      if (!bnd) STG(AbC, 0, kt3, 65536); else if (hasN) STG(AbN, 0, 64, 65536);
      BAR; QUAD(0, 1); BAR;
      // ph7: reads buf1.A1 ; stage buf1.B0
      RDA(1, 1);
      if (!bnd) STG(BbC, 0, kt3, 98304); else if (hasN) STG(BbN, 0, 64, 98304);
      BAR; QUAD(1, 1); BAR;
      // ph8: stage buf1.B1 ; checkpoint
      if (!bnd) STG(BbC, 1, kt3, 114688); else if (hasN) STG(BbN, 1, 64, 114688);
      if (!(bnd && !hasN)) VM6;
      BAR; QUAD(1, 0); BAR;
    }

    // ---- epilogue for finished tile (no LDS; overlaps in-flight staging) ----
    {
      const int rg = lane >> 4;
      float bv[4];
#pragma unroll
      for (int n = 0; n < 4; ++n)
        bv[n] = bias[(size_t)eC * N + nbC * 256 + wc * 64 + n * 16 + r16];
#pragma unroll
      for (int m = 0; m < 8; ++m) {
#pragma unroll
        for (int r = 0; r < 4; ++r) {
          const int lrow = wr * 128 + m * 16 + rg * 4 + r;
          if (MODE == 0) {
            unsigned short* orow = Hout + (size_t)(mbC * 256 + lrow) * N + nbC * 256;
#pragma unroll
            for (int n = 0; n < 4; ++n) {
              float v = acc[m][n][r] + bv[n];
              orow[wc * 64 + n * 16 + r16] = f2bf(fmaxf(v, 0.f));
            }
          } else {
            const int lr = r0C + lrow;
            if (lr < keptC) {
              const int tok = tokmap[mbC * 256 + lrow];
              const float gsc = gate[tok];
              float* orow = Mout + (size_t)tok * N + nbC * 256;
#pragma unroll
              for (int n = 0; n < 4; ++n)
                orow[wc * 64 + n * 16 + r16] = (acc[m][n][r] + bv[n]) * gsc;
            }
          }
        }
      }
#pragma unroll
      for (int m = 0; m < 8; ++m)
#pragma unroll
        for (int n = 0; n < 4; ++n) acc[m][n] = (f32x4){0.f, 0.f, 0.f, 0.f};
    }

    first = false;
    if (!hasN) break;
    // switch cur <- next, then scan for the new next
    tc = tn; mbC = mbN; nbC = nbN; eC = eN; r0C = r0N; keptC = keptN;
    AbC = AbN; BbC = BbN;
    tn = tc + G;
    for (; tn < ntiles; tn += G) {
      tinfo(tn, mbN, nbN, eN, r0N);
      keptN = kept[eN];
      if (r0N < keptN) break;
    }
    hasN = tn < ntiles;
    if (hasN) {
      AbN = A + (size_t)(mbN * 256) * K;
      BbN = BT + ((size_t)eN * N + (size_t)nbN * 256) * K;
    }
  }
}

// ---------------- residual + mean over S ----------------
__global__ __launch_bounds__(256)
void reduce_kernel(const float* __restrict__ X, const float* __restrict__ M2,
                   float* __restrict__ sent) {
  const int c = blockIdx.x * 256 + threadIdx.x;   // 0..1023
  const int b = blockIdx.z;
  const int s0 = blockIdx.y * 128;
  float a = 0.f;
  size_t base = ((size_t)b * S_ + s0) * D_ + c;
  for (int s = 0; s < 128; ++s) a += X[base + (size_t)s * D_] + M2[base + (size_t)s * D_];
  atomicAdd(&sent[b * D_ + c], a * (1.0f / (float)S_));
}

// ---------------- logsumexp NLL loss ----------------
__global__ __launch_bounds__(64)
void loss_kernel(const float* __restrict__ sent, const int* __restrict__ y,
                 float* __restrict__ out) {
  const int lane = threadIdx.x;
  float total = 0.f;
  for (int b = 0; b < B_; ++b) {
    const float* s = sent + b * D_;
    float v[16];
    float mx = -1e30f;
#pragma unroll
    for (int i = 0; i < 16; ++i) { v[i] = s[lane + i * 64]; mx = fmaxf(mx, v[i]); }
#pragma unroll
    for (int sh = 32; sh >= 1; sh >>= 1) mx = fmaxf(mx, __shfl_xor(mx, sh, 64));
    float sm = 0.f;
#pragma unroll
    for (int i = 0; i < 16; ++i) sm += expf(v[i] - mx);
#pragma unroll
    for (int sh = 32; sh >= 1; sh >>= 1) sm += __shfl_xor(sm, sh, 64);
    total += logf(sm) + mx - s[y[b]];
  }
  if (lane == 0) out[0] = total * (1.0f / (float)B_);
}

extern "C" void kernel_launch(void* const* d_in, const int* in_sizes, int n_in,
                              void* d_out, int out_size, void* d_ws, size_t ws_size,
                              hipStream_t stream) {
  const float* x   = (const float*)d_in[0];
  const int*   y   = (const int*)d_in[1];
  const float* wg1 = (const float*)d_in[2];
  const float* w1a = (const float*)d_in[3];
  const float* b1a = (const float*)d_in[4];
  const float* w2a = (const float*)d_in[5];
  const float* b2a = (const float*)d_in[6];
  const float* wg2 = (const float*)d_in[7];
  const float* w1b = (const float*)d_in[8];
  const float* b1b = (const float*)d_in[9];
  const float* w2b = (const float*)d_in[10];
  const float* b2b = (const float*)d_in[11];
  float* out = (float*)d_out;
  (void)in_sizes; (void)n_in; (void)out_size; (void)ws_size;

  char* base = (char*)d_ws;
  size_t o = 0;
  auto alloc = [&](size_t bytes) { size_t r = o; o = (o + bytes + 255) & ~(size_t)255; return r; };
  int*   idx1    = (int*)  (base + alloc((size_t)T_ * 4));
  int*   pos1    = (int*)  (base + alloc((size_t)T_ * 4));
  float* gate1   = (float*)(base + alloc((size_t)T_ * 4));
  int*   idx2    = (int*)  (base + alloc((size_t)T_ * 4));
  int*   pos2    = (int*)  (base + alloc((size_t)T_ * 4));
  float* gate2   = (float*)(base + alloc((size_t)T_ * 4));
  int*   kept1   = (int*)  (base + alloc(64 * 4));
  int*   kept2   = (int*)  (base + alloc(64 * 4));
  int*   tokmap1 = (int*)  (base + alloc((size_t)EC_ * 4));
  int*   tokmap2 = (int*)  (base + alloc((size_t)EC_ * 4));
  float* sent    = (float*)(base + alloc((size_t)B_ * D_ * 4));
  float* m1      = (float*)(base + alloc((size_t)T_ * D_ * 4));   // layer-1 out, reused as layer-2 out
  unsigned short* xbuf = (unsigned short*)(base + alloc((size_t)EC_ * D_ * 2));    // 40 MB
  unsigned short* h    = (unsigned short*)(base + alloc((size_t)EC_ * DFF_ * 2));  // 160 MB
  unsigned short* wT   = (unsigned short*)(base + alloc((size_t)E2_ * D_ * DFF_ * 2)); // 128 MB, reused 4x

  hipMemsetAsync(sent, 0, (size_t)B_ * D_ * 4, stream);

  const int NT0 = (DFF_ / 256) * (EC_ / 256);   // 1280 tiles
  const int NT1 = (D_  / 256) * (EC_ / 256);    // 320 tiles

  // ----- layer 1 (E=8, cap=2560) -----
  gate_kernel<E1_><<<T_ / 4, 256, 0, stream>>>(x, wg1, idx1, gate1);
  scan_kernel<<<1, 1024, 0, stream>>>(idx1, E1_, CAP1_, pos1, kept1);
  scatter_kernel<<<T_, 64, 0, stream>>>(x, idx1, pos1, CAP1_, xbuf, tokmap1, m1);
  wtrans_kernel<<<dim3(DFF_ / 64, D_ / 64, E1_), 256, 0, stream>>>(w1a, wT, D_, DFF_);
  moe_gemm<0><<<256, 512, 0, stream>>>(
      xbuf, wT, b1a, D_, DFF_, CAP1_, DFF_ / 256, NT0, kept1, h, nullptr, nullptr, nullptr);
  wtrans_kernel<<<dim3(D_ / 64, DFF_ / 64, E1_), 256, 0, stream>>>(w2a, wT, DFF_, D_);
  moe_gemm<1><<<256, 512, 0, stream>>>(
      h, wT, b2a, DFF_, D_, CAP1_, D_ / 256, NT1, kept1, nullptr, m1, tokmap1, gate1);

  // ----- layer 2 (E=16, cap=1280) -----
  gate_kernel<E2_><<<T_ / 4, 256, 0, stream>>>(m1, wg2, idx2, gate2);
  scan_kernel<<<1, 1024, 0, stream>>>(idx2, E2_, CAP2_, pos2, kept2);
  scatter_kernel<<<T_, 64, 0, stream>>>(m1, idx2, pos2, CAP2_, xbuf, tokmap2, m1);
  wtrans_kernel<<<dim3(DFF_ / 64, D_ / 64, E2_), 256, 0, stream>>>(w1b, wT, D_, DFF_);
  moe_gemm<0><<<256, 512, 0, stream>>>(
      xbuf, wT, b1b, D_, DFF_, CAP2_, DFF_ / 256, NT0, kept2, h, nullptr, nullptr, nullptr);
  wtrans_kernel<<<dim3(D_ / 64, DFF_ / 64, E2_), 256, 0, stream>>>(w2b, wT, DFF_, D_);
  moe_gemm<1><<<256, 512, 0, stream>>>(
      h, wT, b2b, DFF_, D_, CAP2_, D_ / 256, NT1, kept2, nullptr, m1, tokmap2, gate2);

  // ----- residual + mean + loss -----
  reduce_kernel<<<dim3(D_ / 256, S_ / 128, B_), 256, 0, stream>>>(x, m1, sent);
  loss_kernel<<<1, 64, 0, stream>>>(sent, y, out);
}

// Round 12
// 1292.611 us; speedup vs baseline: 2.1299x; 1.1886x over previous
//
#include <hip/hip_runtime.h>
#include <hip/hip_bf16.h>
#include <cstdint>
#include <cstddef>

#define B_    8
#define S_    2048
#define D_    1024
#define DFF_  4096
#define E1_   8
#define E2_   16
#define T_    (B_*S_)
#define CAP1_ 2560
#define CAP2_ 1280
#define EC_   20480   // E1_*CAP1_ == E2_*CAP2_ == padded expert-buffer rows

typedef __bf16 bf16x8 __attribute__((ext_vector_type(8)));
typedef float  f32x4  __attribute__((ext_vector_type(4)));

__device__ __forceinline__ unsigned short f2bf(float x) {
  return __builtin_bit_cast(unsigned short, (__bf16)x);
}

// ---------------- gating: logits = X @ WG, softmax-max + argmax ----------------
template<int E>
__global__ __launch_bounds__(256)
void gate_kernel(const float* __restrict__ X, const float* __restrict__ WG,
                 int* __restrict__ idxO, float* __restrict__ gateO) {
  const int lane = threadIdx.x & 63;
  const int wv   = threadIdx.x >> 6;
  const int t    = blockIdx.x * 4 + wv;
  const float* xr = X + (size_t)t * D_;
  float acc[E];
#pragma unroll
  for (int e = 0; e < E; ++e) acc[e] = 0.f;
#pragma unroll
  for (int i = 0; i < 4; ++i) {
    float4 xv = *(const float4*)(xr + i * 256 + lane * 4);
    int kb = i * 256 + lane * 4;
#pragma unroll
    for (int j = 0; j < 4; ++j) {
      float xs = (&xv.x)[j];
      const float* wr = WG + (size_t)(kb + j) * E;
#pragma unroll
      for (int e = 0; e < E; ++e) acc[e] += xs * wr[e];
    }
  }
#pragma unroll
  for (int e = 0; e < E; ++e) {
    float v = acc[e];
#pragma unroll
    for (int s = 32; s >= 1; s >>= 1) v += __shfl_xor(v, s, 64);
    acc[e] = v;
  }
  if (lane == 0) {
    float mx = acc[0]; int mi = 0;
#pragma unroll
    for (int e = 1; e < E; ++e) if (acc[e] > mx) { mx = acc[e]; mi = e; }
    float s = 0.f;
#pragma unroll
    for (int e = 0; e < E; ++e) s += expf(acc[e] - mx);
    idxO[t]  = mi;
    gateO[t] = 1.0f / s;   // max softmax prob
  }
}

// ---------------- order-preserving per-expert position scan ----------------
__global__ __launch_bounds__(1024)
void scan_kernel(const int* __restrict__ idx, int E, int cap,
                 int* __restrict__ pos, int* __restrict__ kept) {
  __shared__ int cnt[16][17];
  __shared__ int gbase[16];
  const int tid = threadIdx.x;
  const int w = tid >> 6, lane = tid & 63;
  if (tid < E) gbase[tid] = 0;
  __syncthreads();
  const unsigned long long lt = (lane == 63) ? 0xFFFFFFFFFFFFFFFFull >> 1
                                             : ((1ull << lane) - 1ull);
  for (int it = 0; it < T_ / 1024; ++it) {
    int t = it * 1024 + tid;
    int mi = idx[t];
    int rank = 0;
    for (int e = 0; e < E; ++e) {
      unsigned long long m = __ballot(mi == e);
      if (lane == 0) cnt[w][e] = __popcll(m);
      if (mi == e) rank = __popcll(m & lt);
    }
    __syncthreads();
    int off = 0;
    for (int w2 = 0; w2 < w; ++w2) off += cnt[w2][mi];
    pos[t] = gbase[mi] + off + rank;
    __syncthreads();
    if (tid < E) {
      int tot = 0;
      for (int w2 = 0; w2 < 16; ++w2) tot += cnt[w2][tid];
      gbase[tid] += tot;
    }
    __syncthreads();
  }
  if (tid < E) kept[tid] = min(gbase[tid], cap);
}

// ---------------- scatter tokens to expert buffers (f32 -> bf16) ----------------
__global__ __launch_bounds__(64)
void scatter_kernel(const float* __restrict__ X, const int* __restrict__ idx,
                    const int* __restrict__ pos, int cap,
                    unsigned short* __restrict__ xbuf, int* __restrict__ tokmap,
                    float* __restrict__ mzero) {
  const int t = blockIdx.x;
  const int lane = threadIdx.x;
  const int p = pos[t];
  if (p < cap) {
    const size_t dst = ((size_t)idx[t] * cap + p) * D_;
    const float* xr = X + (size_t)t * D_;
#pragma unroll
    for (int i = 0; i < 4; ++i) {
      float4 v = *(const float4*)(xr + i * 256 + lane * 4);
      ushort4 o;
      o.x = f2bf(v.x); o.y = f2bf(v.y); o.z = f2bf(v.z); o.w = f2bf(v.w);
      *(ushort4*)(xbuf + dst + i * 256 + lane * 4) = o;
    }
    if (lane == 0) tokmap[(size_t)idx[t] * cap + p] = t;
  } else {
    float4 z = {0.f, 0.f, 0.f, 0.f};
    float* mr = mzero + (size_t)t * D_;
#pragma unroll
    for (int i = 0; i < 4; ++i) *(float4*)(mr + i * 256 + lane * 4) = z;
  }
}

// ---------------- weight transpose+convert: [K][N] f32 -> [N][K] bf16 ----------------
__global__ __launch_bounds__(256)
void wtrans_kernel(const float* __restrict__ src, unsigned short* __restrict__ dst,
                   int K, int N) {
  __shared__ float t[64][65];
  const int tid = threadIdx.x;
  const size_t eo = (size_t)blockIdx.z * K * N;
  const int k0 = blockIdx.y * 64, n0 = blockIdx.x * 64;
  const float* s = src + eo + (size_t)k0 * N + n0;
  unsigned short* d = dst + eo + (size_t)n0 * K + k0;
#pragma unroll
  for (int i = 0; i < 4; ++i) {
    int k = i * 16 + (tid >> 4);
    int n4 = (tid & 15) * 4;
    float4 v = *(const float4*)(s + (size_t)k * N + n4);
    t[k][n4] = v.x; t[k][n4 + 1] = v.y; t[k][n4 + 2] = v.z; t[k][n4 + 3] = v.w;
  }
  __syncthreads();
#pragma unroll
  for (int i = 0; i < 4; ++i) {
    int n = i * 16 + (tid >> 4);
    int k4 = (tid & 15) * 4;
    ushort4 o;
    o.x = f2bf(t[k4][n]);     o.y = f2bf(t[k4 + 1][n]);
    o.z = f2bf(t[k4 + 2][n]); o.w = f2bf(t[k4 + 3][n]);
    *(ushort4*)(d + (size_t)n * K + k4) = o;
  }
}

// ---------------- expert GEMM: 256x256 tile, BK=64, 8-phase counted-vmcnt ------
// Round-8 ring + LDS-burst rebalance: B-frags 0,1 read in the 0-read phases
// (ph4/ph8, into separate reg sets) so ph1/ph5 burst 8 reads instead of 12.
#define STG(BASEPTR, H, KT, SLOT) do {                                          \
    const unsigned short* _s = (BASEPTR) + (size_t)((H) * 128) * K + (KT) + st_off; \
    __builtin_amdgcn_global_load_lds((const __attribute__((address_space(1))) void*)_s, \
        (__attribute__((address_space(3))) void*)(smem + (SLOT) + dst0), 16, 0, 0);   \
    __builtin_amdgcn_global_load_lds((const __attribute__((address_space(1))) void*)(_s + (size_t)64 * K), \
        (__attribute__((address_space(3))) void*)(smem + (SLOT) + 8192 + dst0), 16, 0, 0); \
  } while (0)

#define RDA(BUF, MH) do { _Pragma("unroll")                                     \
    for (int m_ = 0; m_ < 4; ++m_) {                                            \
      const char* _p = smem + (BUF) * 65536 + aslot + ((MH) * 4 + m_) * 2048;   \
      af[m_][0] = *(const bf16x8*)(_p + va);                                    \
      af[m_][1] = *(const bf16x8*)(_p + (va ^ 64)); } } while (0)

#define RDB01(BUF, DEST) do { _Pragma("unroll")                                 \
    for (int j_ = 0; j_ < 2; ++j_) {                                            \
      const char* _p = smem + (BUF) * 65536 + bslot + j_ * 2048;                \
      DEST[j_][0] = *(const bf16x8*)(_p + vb);                                  \
      DEST[j_][1] = *(const bf16x8*)(_p + (vb ^ 64)); } } while (0)

#define RDB23(BUF) do { _Pragma("unroll")                                       \
    for (int j_ = 0; j_ < 2; ++j_) {                                            \
      const char* _p = smem + (BUF) * 65536 + bslot + (2 + j_) * 2048;          \
      bfb[j_][0] = *(const bf16x8*)(_p + vb);                                   \
      bfb[j_][1] = *(const bf16x8*)(_p + (vb ^ 64)); } } while (0)

#define QUADN0(MH, BA) do {                                                     \
    __builtin_amdgcn_s_setprio(1);                                              \
    _Pragma("unroll") for (int m_ = 0; m_ < 4; ++m_)                            \
    _Pragma("unroll") for (int j_ = 0; j_ < 2; ++j_)                            \
    _Pragma("unroll") for (int k_ = 0; k_ < 2; ++k_)                            \
      acc[(MH) * 4 + m_][j_] = __builtin_amdgcn_mfma_f32_16x16x32_bf16(         \
          af[m_][k_], BA[j_][k_], acc[(MH) * 4 + m_][j_], 0, 0, 0);             \
    __builtin_amdgcn_s_setprio(0);                                              \
  } while (0)

#define QUADN1(MH) do {                                                         \
    __builtin_amdgcn_s_setprio(1);                                              \
    _Pragma("unroll") for (int m_ = 0; m_ < 4; ++m_)                            \
    _Pragma("unroll") for (int j_ = 0; j_ < 2; ++j_)                            \
    _Pragma("unroll") for (int k_ = 0; k_ < 2; ++k_)                            \
      acc[(MH) * 4 + m_][2 + j_] = __builtin_amdgcn_mfma_f32_16x16x32_bf16(     \
          af[m_][k_], bfb[j_][k_], acc[(MH) * 4 + m_][2 + j_], 0, 0, 0);        \
    __builtin_amdgcn_s_setprio(0);                                              \
  } while (0)

#define SB0   __builtin_amdgcn_sched_barrier(0)
#define BAR   __builtin_amdgcn_s_barrier()
#define VM6   do { asm volatile("s_waitcnt vmcnt(6)" ::: "memory"); SB0; } while (0)
#define VM8   do { asm volatile("s_waitcnt vmcnt(8)" ::: "memory"); SB0; } while (0)
#define VM0   do { asm volatile("s_waitcnt vmcnt(0)" ::: "memory"); SB0; } while (0)

template<int MODE>
__global__ __launch_bounds__(512, 2)
void moe_gemm(const unsigned short* __restrict__ A,
              const unsigned short* __restrict__ BT,
              const float* __restrict__ bias, int K, int N, int cap, int nbcnt,
              const int* __restrict__ kept,
              unsigned short* __restrict__ Hout, float* __restrict__ Mout,
              const int* __restrict__ tokmap, const float* __restrict__ gate) {
  __shared__ char smem[131072];
  const int tid  = threadIdx.x;
  const int lane = tid & 63;
  const int wv   = tid >> 6;      // 0..7
  const int wr   = wv >> 2;       // 0..1 (M half)
  const int wc   = wv & 3;        // 0..3 (N quarter)

  // XCD-chunk swizzle + group-of-4-mb for L2 locality
  const int nwg = gridDim.x;
  const int wg  = (blockIdx.x & 7) * (nwg >> 3) + (blockIdx.x >> 3);
  const int per_grp = nbcnt * 4;
  const int grp = wg / per_grp;
  const int rem = wg - grp * per_grp;
  const int mb  = grp * 4 + (rem & 3);
  const int nb  = rem >> 2;

  const int e  = (mb * 256) / cap;
  const int r0 = mb * 256 - e * cap;
  const int kept_e = kept[e];
  if (r0 >= kept_e) return;
  const unsigned short* Ab = A + (size_t)(mb * 256) * K;
  const unsigned short* Bb = BT + ((size_t)e * N + (size_t)nb * 256) * K;

  f32x4 acc[8][4];
#pragma unroll
  for (int m = 0; m < 8; ++m)
#pragma unroll
    for (int n = 0; n < 4; ++n) acc[m][n] = (f32x4){0.f, 0.f, 0.f, 0.f};

  // staging addressing: chunk row = tid>>3 (0..63), cc = tid&7; src pre-swizzled
  const int scol   = ((tid & 7) ^ ((tid >> 3) & 7)) * 8;
  const size_t st_off = (size_t)(tid >> 3) * K + scol;
  const int dst0   = tid * 16;

  // fragment read addressing
  const int r16 = lane & 15;
  const int g16 = (lane >> 4) * 16;
  const int swz = (r16 & 7) * 16;
  const int va  = r16 * 128 + (g16 ^ swz);
  const int vb  = (wc & 1) * 8192 + va;
  const int aslot = wr * 16384;
  const int bslot = 32768 + (wc >> 1) * 16384;
  bf16x8 af[4][2], bA0[2][2], bA1[2][2], bfb[2][2];

  // slot byte offsets
  //  buf0: A0=0      A1=16384  B0=32768        B1=49152
  //  buf1: A0=65536  A1=81920  B0=98304        B1=114688

  // prologue: stage buf0{A0,B0,B1,A1}, buf1{A0,B0,B1,A1} (tiles 0 and 1)
  STG(Ab, 0, 0, 0);
  STG(Bb, 0, 0, 32768);
  STG(Bb, 1, 0, 49152);
  STG(Ab, 1, 0, 16384);
  STG(Ab, 0, 64, 65536);
  STG(Bb, 0, 64, 98304);
  STG(Bb, 1, 64, 114688);
  STG(Ab, 1, 64, 81920);
  VM8; BAR;   // buf0's 8 loads landed; buf1's 8 outstanding
  RDB01(0, bA0);   // buf0 B-frags 0,1 (landed)

  const int NT = K >> 6;   // 64-wide K-tiles
  const int NI = K >> 7;   // 2 K-tiles per iteration
  for (int i = 0; i < NI; ++i) {
    const bool last = (i == NI - 1);
    const bool s2 = (2 * i + 2) < NT;   // stage tile 2i+2 (into buf0)
    const bool s3 = (2 * i + 3) < NT;   // stage tile 2i+3 (into buf1)
    const int kt1 = (2 * i + 1) << 6;
    const int kt2 = (2 * i + 2) << 6;
    const int kt3 = (2 * i + 3) << 6;

    // ph1: reads buf0.A0 (B01 already in bA0) ; stage buf1.A1 <- tile 2i+1
    RDA(0, 0);
    if (i > 0) STG(Ab, 1, kt1, 81920);
    BAR; QUADN0(0, bA0); BAR;
    // ph2: reads buf0 B-frags 2,3 ; stage buf0.A0 <- tile 2i+2
    RDB23(0);
    if (s2) STG(Ab, 0, kt2, 0);
    BAR; QUADN1(0); BAR;
    // ph3: reads buf0.A1 ; stage buf0.B0 <- tile 2i+2
    RDA(0, 1);
    if (s2) STG(Bb, 0, kt2, 32768);
    BAR; QUADN1(1); BAR;
    // ph4: stage buf0.B1 <- tile 2i+2 ; checkpoint ; pre-read buf1 B-frags 0,1
    if (s2) STG(Bb, 1, kt2, 49152);
    if (last) { VM0; } else { VM6; }
    RDB01(1, bA1);
    BAR; QUADN0(1, bA0); BAR;
    // ph5: reads buf1.A0 ; stage buf0.A1 <- tile 2i+2
    RDA(1, 0);
    if (s2) STG(Ab, 1, kt2, 16384);
    BAR; QUADN0(0, bA1); BAR;
    // ph6: reads buf1 B-frags 2,3 ; stage buf1.A0 <- tile 2i+3
    RDB23(1);
    if (s3) STG(Ab, 0, kt3, 65536);
    BAR; QUADN1(0); BAR;
    // ph7: reads buf1.A1 ; stage buf1.B0 <- tile 2i+3
    RDA(1, 1);
    if (s3) STG(Bb, 0, kt3, 98304);
    BAR; QUADN1(1); BAR;
    // ph8: stage buf1.B1 <- tile 2i+3 ; checkpoint ; pre-read buf0 B-frags 0,1
    if (s3) STG(Bb, 1, kt3, 114688);
    if (!last) { VM6; RDB01(0, bA0); }
    BAR; QUADN0(1, bA1); BAR;
  }

  // epilogue
  const int rg = lane >> 4;
  float bv[4];
#pragma unroll
  for (int n = 0; n < 4; ++n)
    bv[n] = bias[(size_t)e * N + nb * 256 + wc * 64 + n * 16 + r16];

#pragma unroll
  for (int m = 0; m < 8; ++m) {
#pragma unroll
    for (int r = 0; r < 4; ++r) {
      const int lrow = wr * 128 + m * 16 + rg * 4 + r;
      if (MODE == 0) {
        unsigned short* orow = Hout + (size_t)(mb * 256 + lrow) * N + nb * 256;
#pragma unroll
        for (int n = 0; n < 4; ++n) {
          float v = acc[m][n][r] + bv[n];
          orow[wc * 64 + n * 16 + r16] = f2bf(fmaxf(v, 0.f));
        }
      } else {
        const int lr = r0 + lrow;
        if (lr < kept_e) {
          const int tok = tokmap[mb * 256 + lrow];
          const float gsc = gate[tok];
          float* orow = Mout + (size_t)tok * N + nb * 256;
#pragma unroll
          for (int n = 0; n < 4; ++n)
            orow[wc * 64 + n * 16 + r16] = (acc[m][n][r] + bv[n]) * gsc;
        }
      }
    }
  }
}

// ---------------- residual + mean over S ----------------
__global__ __launch_bounds__(256)
void reduce_kernel(const float* __restrict__ X, const float* __restrict__ M2,
                   float* __restrict__ sent) {
  const int c = blockIdx.x * 256 + threadIdx.x;   // 0..1023
  const int b = blockIdx.z;
  const int s0 = blockIdx.y * 128;
  float a = 0.f;
  size_t base = ((size_t)b * S_ + s0) * D_ + c;
  for (int s = 0; s < 128; ++s) a += X[base + (size_t)s * D_] + M2[base + (size_t)s * D_];
  atomicAdd(&sent[b * D_ + c], a * (1.0f / (float)S_));
}

// ---------------- logsumexp NLL loss ----------------
__global__ __launch_bounds__(64)
void loss_kernel(const float* __restrict__ sent, const int* __restrict__ y,
                 float* __restrict__ out) {
  const int lane = threadIdx.x;
  float total = 0.f;
  for (int b = 0; b < B_; ++b) {
    const float* s = sent + b * D_;
    float v[16];
    float mx = -1e30f;
#pragma unroll
    for (int i = 0; i < 16; ++i) { v[i] = s[lane + i * 64]; mx = fmaxf(mx, v[i]); }
#pragma unroll
    for (int sh = 32; sh >= 1; sh >>= 1) mx = fmaxf(mx, __shfl_xor(mx, sh, 64));
    float sm = 0.f;
#pragma unroll
    for (int i = 0; i < 16; ++i) sm += expf(v[i] - mx);
#pragma unroll
    for (int sh = 32; sh >= 1; sh >>= 1) sm += __shfl_xor(sm, sh, 64);
    total += logf(sm) + mx - s[y[b]];
  }
  if (lane == 0) out[0] = total * (1.0f / (float)B_);
}

extern "C" void kernel_launch(void* const* d_in, const int* in_sizes, int n_in,
                              void* d_out, int out_size, void* d_ws, size_t ws_size,
                              hipStream_t stream) {
  const float* x   = (const float*)d_in[0];
  const int*   y   = (const int*)d_in[1];
  const float* wg1 = (const float*)d_in[2];
  const float* w1a = (const float*)d_in[3];
  const float* b1a = (const float*)d_in[4];
  const float* w2a = (const float*)d_in[5];
  const float* b2a = (const float*)d_in[6];
  const float* wg2 = (const float*)d_in[7];
  const float* w1b = (const float*)d_in[8];
  const float* b1b = (const float*)d_in[9];
  const float* w2b = (const float*)d_in[10];
  const float* b2b = (const float*)d_in[11];
  float* out = (float*)d_out;
  (void)in_sizes; (void)n_in; (void)out_size; (void)ws_size;

  char* base = (char*)d_ws;
  size_t o = 0;
  auto alloc = [&](size_t bytes) { size_t r = o; o = (o + bytes + 255) & ~(size_t)255; return r; };
  int*   idx1    = (int*)  (base + alloc((size_t)T_ * 4));
  int*   pos1    = (int*)  (base + alloc((size_t)T_ * 4));
  float* gate1   = (float*)(base + alloc((size_t)T_ * 4));
  int*   idx2    = (int*)  (base + alloc((size_t)T_ * 4));
  int*   pos2    = (int*)  (base + alloc((size_t)T_ * 4));
  float* gate2   = (float*)(base + alloc((size_t)T_ * 4));
  int*   kept1   = (int*)  (base + alloc(64 * 4));
  int*   kept2   = (int*)  (base + alloc(64 * 4));
  int*   tokmap1 = (int*)  (base + alloc((size_t)EC_ * 4));
  int*   tokmap2 = (int*)  (base + alloc((size_t)EC_ * 4));
  float* sent    = (float*)(base + alloc((size_t)B_ * D_ * 4));
  float* m1      = (float*)(base + alloc((size_t)T_ * D_ * 4));   // layer-1 out, reused as layer-2 out
  unsigned short* xbuf = (unsigned short*)(base + alloc((size_t)EC_ * D_ * 2));    // 40 MB
  unsigned short* h    = (unsigned short*)(base + alloc((size_t)EC_ * DFF_ * 2));  // 160 MB
  unsigned short* wT   = (unsigned short*)(base + alloc((size_t)E2_ * D_ * DFF_ * 2)); // 128 MB, reused 4x

  hipMemsetAsync(sent, 0, (size_t)B_ * D_ * 4, stream);

  // ----- layer 1 (E=8, cap=2560) -----
  gate_kernel<E1_><<<T_ / 4, 256, 0, stream>>>(x, wg1, idx1, gate1);
  scan_kernel<<<1, 1024, 0, stream>>>(idx1, E1_, CAP1_, pos1, kept1);
  scatter_kernel<<<T_, 64, 0, stream>>>(x, idx1, pos1, CAP1_, xbuf, tokmap1, m1);
  wtrans_kernel<<<dim3(DFF_ / 64, D_ / 64, E1_), 256, 0, stream>>>(w1a, wT, D_, DFF_);
  moe_gemm<0><<<(DFF_ / 256) * (EC_ / 256), 512, 0, stream>>>(
      xbuf, wT, b1a, D_, DFF_, CAP1_, DFF_ / 256, kept1, h, nullptr, nullptr, nullptr);
  wtrans_kernel<<<dim3(D_ / 64, DFF_ / 64, E1_), 256, 0, stream>>>(w2a, wT, DFF_, D_);
  moe_gemm<1><<<(D_ / 256) * (EC_ / 256), 512, 0, stream>>>(
      h, wT, b2a, DFF_, D_, CAP1_, D_ / 256, kept1, nullptr, m1, tokmap1, gate1);

  // ----- layer 2 (E=16, cap=1280) -----
  gate_kernel<E2_><<<T_ / 4, 256, 0, stream>>>(m1, wg2, idx2, gate2);
  scan_kernel<<<1, 1024, 0, stream>>>(idx2, E2_, CAP2_, pos2, kept2);
  scatter_kernel<<<T_, 64, 0, stream>>>(m1, idx2, pos2, CAP2_, xbuf, tokmap2, m1);
  wtrans_kernel<<<dim3(DFF_ / 64, D_ / 64, E2_), 256, 0, stream>>>(w1b, wT, D_, DFF_);
  moe_gemm<0><<<(DFF_ / 256) * (EC_ / 256), 512, 0, stream>>>(
      xbuf, wT, b1b, D_, DFF_, CAP2_, DFF_ / 256, kept2, h, nullptr, nullptr, nullptr);
  wtrans_kernel<<<dim3(D_ / 64, DFF_ / 64, E2_), 256, 0, stream>>>(w2b, wT, DFF_, D_);
  moe_gemm<1><<<(D_ / 256) * (EC_ / 256), 512, 0, stream>>>(
      h, wT, b2b, DFF_, D_, CAP2_, D_ / 256, kept2, nullptr, m1, tokmap2, gate2);

  // ----- residual + mean + loss -----
  reduce_kernel<<<dim3(D_ / 256, S_ / 128, B_), 256, 0, stream>>>(x, m1, sent);
  loss_kernel<<<1, 64, 0, stream>>>(sent, y, out);
}